// Round 5
// baseline (329.386 us; speedup 1.0000x reference)
//
#include <hip/hip_runtime.h>
#include <hip/hip_bf16.h>
#include <math.h>

#define BB 2
#define TT 2048
#define CC 1024
#define NH 16
#define HD 64
#define BT (BB*TT)          // 4096 rows
#define LN_EPS 1e-5f
#define ATT_SCALE 0.03125f  // C^-0.5 (reference scales by full C, not head_size)

typedef __bf16 bf16x8 __attribute__((ext_vector_type(8)));
typedef __bf16 bf16x4 __attribute__((ext_vector_type(4)));
typedef short shortx4 __attribute__((ext_vector_type(4)));
typedef float floatx4 __attribute__((ext_vector_type(4)));

__device__ __forceinline__ void gl_lds16(const __bf16* g, __bf16* l) {
    __builtin_amdgcn_global_load_lds((const __attribute__((address_space(1))) void*)g,
                                     (__attribute__((address_space(3))) void*)l,
                                     16, 0, 0);
}

#define MFMA32(a, b, c) __builtin_amdgcn_mfma_f32_16x16x32_bf16(a, b, c, 0, 0, 0)

#if __has_builtin(__builtin_amdgcn_mfma_f32_16x16x16_bf16)
__device__ __forceinline__ floatx4 mfma16(bf16x4 a, bf16x4 b, floatx4 c) {
    return __builtin_amdgcn_mfma_f32_16x16x16_bf16(a, b, c, 0, 0, 0);
}
#else
__device__ __forceinline__ floatx4 mfma16(bf16x4 a, bf16x4 b, floatx4 c) {
    return __builtin_amdgcn_mfma_f32_16x16x16bf16_1k(
        __builtin_bit_cast(shortx4, a), __builtin_bit_cast(shortx4, b), c, 0, 0, 0);
}
#endif

#define BARRIER() __builtin_amdgcn_s_barrier()
#define MEMF()  asm volatile("" ::: "memory")
#define LGKM0() asm volatile("s_waitcnt lgkmcnt(0)" ::: "memory")
#define VM4()   asm volatile("s_waitcnt vmcnt(4)" ::: "memory")
#define VM0()   asm volatile("s_waitcnt vmcnt(0)" ::: "memory")

// XCD-aware block remap (grid totals are multiples of 8 -> bijective).
__device__ __forceinline__ void swizzle_xcd(int& xb, int& yb, int& zb) {
    int nx = gridDim.x, ny = gridDim.y;
    int total = nx * ny * (int)gridDim.z;
    int lin = blockIdx.x + nx * (blockIdx.y + ny * blockIdx.z);
    int c = lin & 7, s = lin >> 3;
    int idx = c * (total >> 3) + s;
    xb = idx % nx;
    yb = (idx / nx) % ny;
    zb = idx / (nx * ny);
}

// ---------------------------------------------------------------------------
// Fused: all weight transposes (idx < 12288) + ln1 (idx >= 12288).
// ---------------------------------------------------------------------------
__global__ __launch_bounds__(256) void transpose_ln(
        const float* __restrict__ Wq, const float* __restrict__ Wk,
        const float* __restrict__ Wv, const float* __restrict__ Wo,
        const float* __restrict__ W1, const float* __restrict__ W2,
        __bf16* __restrict__ WqkvT, __bf16* __restrict__ WoT,
        __bf16* __restrict__ W1T, __bf16* __restrict__ W2T,
        const float* __restrict__ x, const float* __restrict__ g1,
        const float* __restrict__ be1, __bf16* __restrict__ hb) {
    __shared__ float t[32][33];
    __shared__ float rs_[4], rss_[4];
    __shared__ float mu_s, inv_s;
    int idx = blockIdx.x;
    if (idx >= 12288) {
        int row = idx - 12288;
        const float4* xr = (const float4*)(x + (size_t)row * CC);
        float4 v = xr[threadIdx.x];
        float s  = v.x + v.y + v.z + v.w;
        float ss = v.x*v.x + v.y*v.y + v.z*v.z + v.w*v.w;
        #pragma unroll
        for (int off = 32; off; off >>= 1) {
            s  += __shfl_down(s, off);
            ss += __shfl_down(ss, off);
        }
        int lane = threadIdx.x & 63, wid = threadIdx.x >> 6;
        if (lane == 0) { rs_[wid] = s; rss_[wid] = ss; }
        __syncthreads();
        if (threadIdx.x == 0) {
            float S  = rs_[0] + rs_[1] + rs_[2] + rs_[3];
            float SS = rss_[0] + rss_[1] + rss_[2] + rss_[3];
            float mu  = S * (1.0f / CC);
            float var = SS * (1.0f / CC) - mu * mu;
            mu_s  = mu;
            inv_s = rsqrtf(var + LN_EPS);
        }
        __syncthreads();
        float mu = mu_s, inv = inv_s;
        float4 gv = ((const float4*)g1)[threadIdx.x];
        float4 bv = ((const float4*)be1)[threadIdx.x];
        bf16x4 o;
        o[0] = (__bf16)((v.x - mu) * inv * gv.x + bv.x);
        o[1] = (__bf16)((v.y - mu) * inv * gv.y + bv.y);
        o[2] = (__bf16)((v.z - mu) * inv * gv.z + bv.z);
        o[3] = (__bf16)((v.w - mu) * inv * gv.w + bv.w);
        *(bf16x4*)(hb + (size_t)row * CC + threadIdx.x * 4) = o;
        return;
    }
    const float* src; __bf16* dst; int K, N, tn, tk;
    if (idx < 3072) {
        int wsel = idx >> 10, local = idx & 1023;
        src = (wsel == 0) ? Wq : (wsel == 1 ? Wk : Wv);
        dst = WqkvT + (size_t)wsel * 1024 * 1024;
        K = 1024; N = 1024; tn = local & 31; tk = local >> 5;
    } else if (idx < 4096) {
        int local = idx - 3072;
        src = Wo; dst = WoT; K = 1024; N = 1024; tn = local & 31; tk = local >> 5;
    } else if (idx < 8192) {
        int local = idx - 4096;
        src = W1; dst = W1T; K = 1024; N = 4096; tn = local & 127; tk = local >> 7;
    } else {
        int local = idx - 8192;
        src = W2; dst = W2T; K = 4096; N = 1024; tn = local & 31; tk = local >> 5;
    }
    int n0 = tn * 32, k0 = tk * 32;
    int tx = threadIdx.x & 31, ty = threadIdx.x >> 5;
    #pragma unroll
    for (int r = ty; r < 32; r += 8)
        t[r][tx] = src[(size_t)(k0 + r) * N + n0 + tx];
    __syncthreads();
    #pragma unroll
    for (int r = ty; r < 32; r += 8)
        dst[(size_t)(n0 + r) * K + k0 + tx] = (__bf16)t[tx][r];
}

// ---------------------------------------------------------------------------
// Reduce 4 bf16 split-K partials + bias + residual -> x2 (fp32), then LN -> hb.
// ---------------------------------------------------------------------------
__global__ __launch_bounds__(256) void reduce_wo_ln(const __bf16* __restrict__ P,
                                                    const float* __restrict__ bo,
                                                    const float* __restrict__ x,
                                                    const float* __restrict__ g2,
                                                    const float* __restrict__ be2,
                                                    float* __restrict__ x2,
                                                    __bf16* __restrict__ hb) {
    int row = blockIdx.x;
    int c = threadIdx.x * 4;
    const size_t S = (size_t)BT * CC;
    float4 xb = *(const float4*)(x + (size_t)row * CC + c);
    float4 bb = *(const float4*)(bo + c);
    float4 v;
    v.x = xb.x + bb.x;
    v.y = xb.y + bb.y;
    v.z = xb.z + bb.z;
    v.w = xb.w + bb.w;
    #pragma unroll
    for (int z = 0; z < 4; ++z) {
        bf16x4 a = *(const bf16x4*)(P + z * S + (size_t)row * CC + c);
        v.x += (float)a[0]; v.y += (float)a[1]; v.z += (float)a[2]; v.w += (float)a[3];
    }
    *(float4*)(x2 + (size_t)row * CC + c) = v;

    float s  = v.x + v.y + v.z + v.w;
    float ss = v.x*v.x + v.y*v.y + v.z*v.z + v.w*v.w;
    #pragma unroll
    for (int off = 32; off; off >>= 1) {
        s  += __shfl_down(s, off);
        ss += __shfl_down(ss, off);
    }
    __shared__ float rs_[4], rss_[4];
    __shared__ float mu_s, inv_s;
    int lane = threadIdx.x & 63, wid = threadIdx.x >> 6;
    if (lane == 0) { rs_[wid] = s; rss_[wid] = ss; }
    __syncthreads();
    if (threadIdx.x == 0) {
        float S_  = rs_[0] + rs_[1] + rs_[2] + rs_[3];
        float SS = rss_[0] + rss_[1] + rss_[2] + rss_[3];
        float mu  = S_ * (1.0f / CC);
        float var = SS * (1.0f / CC) - mu * mu;
        mu_s  = mu;
        inv_s = rsqrtf(var + LN_EPS);
    }
    __syncthreads();
    float mu = mu_s, inv = inv_s;
    float4 gv = ((const float4*)g2)[threadIdx.x];
    float4 bv = ((const float4*)be2)[threadIdx.x];
    bf16x4 o;
    o[0] = (__bf16)((v.x - mu) * inv * gv.x + bv.x);
    o[1] = (__bf16)((v.y - mu) * inv * gv.y + bv.y);
    o[2] = (__bf16)((v.z - mu) * inv * gv.z + bv.z);
    o[3] = (__bf16)((v.w - mu) * inv * gv.w + bv.w);
    *(bf16x4*)(hb + (size_t)row * CC + c) = o;
}

// ---------------------------------------------------------------------------
// Reduce 4 bf16 split-K partials + bias + residual(x2) -> out (fp32).
// ---------------------------------------------------------------------------
__global__ __launch_bounds__(256) void reduce_ffn(const __bf16* __restrict__ P,
                                                  const float* __restrict__ b2,
                                                  const float* __restrict__ x2,
                                                  float* __restrict__ out) {
    int row = blockIdx.x;
    int c = threadIdx.x * 4;
    const size_t S = (size_t)BT * CC;
    float4 v = *(const float4*)(x2 + (size_t)row * CC + c);
    float4 bb = *(const float4*)(b2 + c);
    v.x += bb.x; v.y += bb.y; v.z += bb.z; v.w += bb.w;
    #pragma unroll
    for (int z = 0; z < 4; ++z) {
        bf16x4 a = *(const bf16x4*)(P + z * S + (size_t)row * CC + c);
        v.x += (float)a[0]; v.y += (float)a[1]; v.z += (float)a[2]; v.w += (float)a[3];
    }
    *(float4*)(out + (size_t)row * CC + c) = v;
}

// ---------------------------------------------------------------------------
// 256x256-tile / BK=64 / 8-wave / 8-phase counted-vmcnt GEMM (round 10).
// Operand reuse across phases: Q00(A0+B0), Q01(B1), Q11(A1), Q10(none).
// 24 ds_read_b128 per K-step/wave. vmcnt(4) at phi4/phi8. Chunk-XOR swizzle
// carried on the global source; 0 bank conflicts measured.
// VSPLIT epilogue pre-scales q columns (col<1024) by 2^-5 (= C^-0.5).
// ---------------------------------------------------------------------------
__device__ __forceinline__ void stage_half(const __bf16* __restrict__ mat, int row0,
                                           int ldk, int k0, __bf16* lds, int tid) {
    int r = tid >> 3;                       // 0..63
    int lch = (tid & 7) ^ (r & 7);          // logical k-chunk for phys chunk tid&7
    const __bf16* gp = mat + (size_t)(row0 + r) * ldk + k0 + lch * 8;
    gl_lds16(gp, lds + tid * 8);                           // rows 0..63
    gl_lds16(gp + (size_t)64 * ldk, lds + 4096 + tid * 8); // rows 64..127
}

__device__ __forceinline__ void load_a(const __bf16* As_, int qr, int wr, int m, int g,
                                       bf16x8 (&fa)[4][2]) {
    #pragma unroll
    for (int i = 0; i < 4; ++i) {
        int ra = qr * 128 + wr * 64 + i * 16 + m;
        #pragma unroll
        for (int kk = 0; kk < 2; ++kk)
            fa[i][kk] = *(const bf16x8*)&As_[ra * 64 + (((kk * 4 + g) ^ (m & 7)) * 8)];
    }
}

__device__ __forceinline__ void load_b(const __bf16* Bs_, int qc, int wc, int m, int g,
                                       bf16x8 (&fb)[2][2]) {
    #pragma unroll
    for (int j = 0; j < 2; ++j) {
        int rb = qc * 128 + wc * 32 + j * 16 + m;
        #pragma unroll
        for (int kk = 0; kk < 2; ++kk)
            fb[j][kk] = *(const bf16x8*)&Bs_[rb * 64 + (((kk * 4 + g) ^ (m & 7)) * 8)];
    }
}

__device__ __forceinline__ void mfma_q(bf16x8 (&fa)[4][2], bf16x8 (&fb)[2][2],
                                       floatx4 (&a)[4][2]) {
    __builtin_amdgcn_s_setprio(1);
    #pragma unroll
    for (int i = 0; i < 4; ++i)
        #pragma unroll
        for (int j = 0; j < 2; ++j)
            #pragma unroll
            for (int kk = 0; kk < 2; ++kk)
                a[i][j] = MFMA32(fa[i][kk], fb[j][kk], a[i][j]);
    __builtin_amdgcn_s_setprio(0);
}

template<int SK, typename OT, bool BIAS, bool RELU, bool VSPLIT>
__global__ __launch_bounds__(512, 2) void gemm256(const __bf16* __restrict__ A,
                                                  const __bf16* __restrict__ Bt,
                                                  const float* __restrict__ bias,
                                                  OT* __restrict__ C,
                                                  __bf16* __restrict__ vt,
                                                  int M, int N, int K) {
    __shared__ __bf16 As[2][16384];   // [buf][256 rows x 64], 32 KiB each
    __shared__ __bf16 Bs[2][16384];
    int bx, by, bz;
    swizzle_xcd(bx, by, bz);
    const int tid = threadIdx.x;
    const int l = tid & 63, w = tid >> 6;
    const int m = l & 15, g = l >> 4;
    const int wr = w >> 2, wc = w & 3;          // 2x4 wave grid
    const int m0 = by * 256, n0 = bx * 256;
    const int Keff = K / SK;
    const int kb = (SK > 1) ? bz * Keff : 0;
    const int iters = Keff >> 7;                // 2 K-tiles (128) per iter

    floatx4 acc[2][2][4][2];
    #pragma unroll
    for (int a = 0; a < 2; ++a)
        #pragma unroll
        for (int b = 0; b < 2; ++b)
            #pragma unroll
            for (int i = 0; i < 4; ++i)
                #pragma unroll
                for (int j = 0; j < 2; ++j) {
                    floatx4 z = {0.f, 0.f, 0.f, 0.f};
                    acc[a][b][i][j] = z;
                }

    // prologue: t0 fully + t1.{A-lo, B-hi}; vmcnt(4) retires t0's 8 loads.
    stage_half(A,  m0,       K, kb,      &As[0][0],    tid);  // t0.A-lo
    stage_half(Bt, n0,       K, kb,      &Bs[0][0],    tid);  // t0.B-lo
    stage_half(Bt, n0 + 128, K, kb,      &Bs[0][8192], tid);  // t0.B-hi
    stage_half(A,  m0 + 128, K, kb,      &As[0][8192], tid);  // t0.A-hi
    stage_half(A,  m0,       K, kb + 64, &As[1][0],    tid);  // t1.A-lo
    stage_half(Bt, n0 + 128, K, kb + 64, &Bs[1][8192], tid);  // t1.B-hi
    VM4(); BARRIER(); MEMF();

    bf16x8 fa[4][2], fbA[2][2], fbB[2][2];

    for (int it = 0; it < iters; ++it) {
        const bool lastI = (it == iters - 1);
        const int kB = kb + (2 * it + 1) * 64;  // tile tb = 2it+1 (buf1)
        const int kC = kB + 64;                 // tile tc = 2it+2 (buf0)
        const int kD = kC + 64;                 // tile td = 2it+3 (buf1)

        // ---- buf0 (tile ta) ----
        load_a(&As[0][0], 0, wr, m, g, fa);
        load_b(&Bs[0][0], 0, wc, m, g, fbA);
        stage_half(Bt, n0, K, kB, &Bs[1][0], tid);               // tb.B-lo
        BARRIER(); LGKM0(); mfma_q(fa, fbA, acc[0][0]); BARRIER(); MEMF();
        load_b(&Bs[0][0], 1, wc, m, g, fbB);
        stage_half(A, m0 + 128, K, kB, &As[1][8192], tid);       // tb.A-hi
        BARRIER(); LGKM0(); mfma_q(fa, fbB, acc[0][1]); BARRIER(); MEMF();
        load_a(&As[0][0], 1, wr, m, g, fa);
        if (!lastI) stage_half(A, m0, K, kC, &As[0][0], tid);    // tc.A-lo
        BARRIER(); LGKM0(); mfma_q(fa, fbB, acc[1][1]); BARRIER(); MEMF();
        if (!lastI) { stage_half(Bt, n0 + 128, K, kC, &Bs[0][8192], tid); // tc.B-hi
                      VM4(); }
        else VM0();                              // drain: tb fully resident
        BARRIER(); mfma_q(fa, fbA, acc[1][0]); BARRIER(); MEMF();

        // ---- buf1 (tile tb) ----
        load_a(&As[1][0], 0, wr, m, g, fa);
        load_b(&Bs[1][0], 0, wc, m, g, fbA);
        if (!lastI) stage_half(Bt, n0, K, kC, &Bs[0][0], tid);   // tc.B-lo
        BARRIER(); LGKM0(); mfma_q(fa, fbA, acc[0][0]); BARRIER(); MEMF();
        load_b(&Bs[1][0], 1, wc, m, g, fbB);
        if (!lastI) stage_half(A, m0 + 128, K, kC, &As[0][8192], tid); // tc.A-hi
        BARRIER(); LGKM0(); mfma_q(fa, fbB, acc[0][1]); BARRIER(); MEMF();
        load_a(&As[1][0], 1, wr, m, g, fa);
        if (!lastI) stage_half(A, m0, K, kD, &As[1][0], tid);    // td.A-lo
        BARRIER(); LGKM0(); mfma_q(fa, fbB, acc[1][1]); BARRIER(); MEMF();
        if (!lastI) { stage_half(Bt, n0 + 128, K, kD, &Bs[1][8192], tid); // td.B-hi
                      VM4(); }                   // retires tc; td in flight
        BARRIER(); mfma_q(fa, fbA, acc[1][0]); BARRIER(); MEMF();
    }

    // ---- epilogue ----
    if (SK > 1) {
        __bf16* P = (__bf16*)C + (size_t)bz * M * N;
        #pragma unroll
        for (int qr = 0; qr < 2; ++qr)
            #pragma unroll
            for (int i = 0; i < 4; ++i) {
                int row = m0 + qr * 128 + wr * 64 + i * 16 + g * 4;
                #pragma unroll
                for (int qc = 0; qc < 2; ++qc)
                    #pragma unroll
                    for (int j = 0; j < 2; ++j) {
                        int col = n0 + qc * 128 + wc * 32 + j * 16 + m;
                        #pragma unroll
                        for (int r = 0; r < 4; ++r)
                            P[(size_t)(row + r) * N + col] = (__bf16)acc[qr][qc][i][j][r];
                    }
            }
    } else if (VSPLIT && n0 >= 2048) {
        #pragma unroll
        for (int qr = 0; qr < 2; ++qr)
            #pragma unroll
            for (int i = 0; i < 4; ++i) {
                int row = m0 + qr * 128 + wr * 64 + i * 16 + g * 4;
                int bb = row >> 11, t0 = row & 2047;
                #pragma unroll
                for (int qc = 0; qc < 2; ++qc)
                    #pragma unroll
                    for (int j = 0; j < 2; ++j) {
                        int cv = n0 + qc * 128 + wc * 32 + j * 16 + m - 2048;
                        bf16x4 o;
                        #pragma unroll
                        for (int r = 0; r < 4; ++r) o[r] = (__bf16)acc[qr][qc][i][j][r];
                        *(bf16x4*)(vt + ((size_t)(bb * NH + (cv >> 6)) * HD + (cv & 63)) * 2048 + t0) = o;
                    }
            }
    } else {
        #pragma unroll
        for (int qr = 0; qr < 2; ++qr)
            #pragma unroll
            for (int i = 0; i < 4; ++i) {
                int row = m0 + qr * 128 + wr * 64 + i * 16 + g * 4;
                #pragma unroll
                for (int qc = 0; qc < 2; ++qc)
                    #pragma unroll
                    for (int j = 0; j < 2; ++j) {
                        int col = n0 + qc * 128 + wc * 32 + j * 16 + m;
                        float bv = BIAS ? bias[col] : 0.0f;
                        #pragma unroll
                        for (int r = 0; r < 4; ++r) {
                            float vo = acc[qr][qc][i][j][r] + bv;
                            if (RELU) vo = fmaxf(vo, 0.0f);
                            if (VSPLIT && col < 1024) vo *= ATT_SCALE;  // pre-scale q
                            C[(size_t)(row + r) * N + col] = (OT)vo;
                        }
                    }
            }
    }
}

// ---------------------------------------------------------------------------
// Flash attention v6 (round 13). Round-12 structure (64-row q-subtiles,
// 4 blocks/CU) + two LDS/L2 fixes:
//  (1) Head-locality XCD remap: blockIdx%8 = h%8 -> each XCD's L2 serves
//      4 (b,h) K/V pairs (2 MB, L2-resident). Was q0%8 -> K/V replicated
//      into all 8 XCD L2s (FETCH 80 MB).
//  (2) V reg-staged (global->VGPR->ds_write_b128) with FULL 2-bit swizzle:
//      phys slot16 = slot ^ ((d>>2)&1), 8B halves swapped when (d>>3)&1.
//      PV read uses bit1=(g>>1)^((m>>2)&1), bit0=(g&1)^((m>>3)&1): each
//      16-lane phase hits all 32 banks once -> zero conflicts (was 4-way;
//      gl_lds couldn't carry the 8B-granular bit). V loads for kt+1 issue
//      before compute of kt -> HBM/L2 latency hidden (T14).
// K staging unchanged (gl_lds, conflict-free pattern).
// ---------------------------------------------------------------------------
__global__ __launch_bounds__(256, 4) void attn_mfma6(const __bf16* __restrict__ qkv,
                                                     const __bf16* __restrict__ vt,
                                                     __bf16* __restrict__ att) {
    const int p = blockIdx.x;
    const int h    = (p & 7) + 8 * ((p >> 7) & 1);
    const int q0   = (p >> 3) & 15;
    const int b    = (p >> 8) & 1;
    const int half = p >> 9;
    const int qs = half ? 31 - q0 : q0;     // 64-row q-subtile, 0..31

    const int tid = threadIdx.x;
    const int l = tid & 63, w = tid >> 6;   // wave w owns q-rows qs*64 + w*16 ..+15
    const int m = l & 15, g = l >> 4;

    __shared__ __bf16 Ks[2][128][32];   // [d-half][k-row][32], 4-chunk XOR swz
    __shared__ __bf16 Vt3[8][64][16];   // [k16][d][k-elem], 2-bit swizzled

    const __bf16* qp = qkv + (size_t)b * TT * 3072 + h * HD;
    const __bf16* kp = qp + 1024;
    const __bf16* vh = vt + (size_t)(b * NH + h) * HD * 2048;

    // V staging map: thread covers rows d0,d0+1 of k16-block jts (64B).
    const int jts = tid >> 5;               // 0..7
    const int r5  = tid & 31;
    const int d0  = r5 * 2;
    const __bf16* vbase = vh + (size_t)d0 * 2048 + jts * 16;

    bf16x8 qb0, qb1;
    {
        int qrow = qs * 64 + w * 16 + m;
        qb0 = *(const bf16x8*)(qp + (size_t)qrow * 3072 + g * 8);
        qb1 = *(const bf16x8*)(qp + (size_t)qrow * 3072 + 32 + g * 8);
    }

    floatx4 O[4];
    float l_s = 0.0f;
    #pragma unroll
    for (int jd = 0; jd < 4; ++jd) { floatx4 z = {0.f, 0.f, 0.f, 0.f}; O[jd] = z; }

    bf16x8 vreg[4];
    // prologue: V loads for kt=0
    vreg[0] = *(const bf16x8*)(vbase);
    vreg[1] = *(const bf16x8*)(vbase + 8);
    vreg[2] = *(const bf16x8*)(vbase + 2048);
    vreg[3] = *(const bf16x8*)(vbase + 2048 + 8);

    const int ktmax = qs >> 1;
    for (int kt = 0; kt <= ktmax; ++kt) {
        __syncthreads();                     // prev compute done (WAR)
        // K: gl_lds staging (unchanged)
        #pragma unroll
        for (int c = 0; c < 4; ++c) {
            int idx = w * 4 + c;
            int dh = idx >> 3, k16 = idx & 7;
            gl_lds16(kp + (size_t)(kt * 128 + k16 * 16 + (l >> 2)) * 3072
                        + dh * 32 + (((l & 3) ^ ((l >> 3) & 3)) * 8),
                     (__bf16*)Ks + dh * 4096 + k16 * 512);
        }
        // V: write staged regs (compiler waits vreg's loads, K gl_lds fly on)
        #pragma unroll
        for (int dd = 0; dd < 2; ++dd) {
            int d = d0 + dd;
            int s16 = (d >> 2) & 1, s8 = (d >> 3) & 1;
            #pragma unroll
            for (int sl = 0; sl < 2; ++sl) {
                bf16x8 v = vreg[dd * 2 + sl];
                if (s8) {
                    bf16x8 t = {v[4], v[5], v[6], v[7], v[0], v[1], v[2], v[3]};
                    v = t;
                }
                *(bf16x8*)&Vt3[jts][d][(sl ^ s16) * 8] = v;
            }
        }
        __syncthreads();                     // K landed + V writes visible
        if (kt < ktmax) {                    // issue-early V loads for kt+1
            const __bf16* vs = vbase + (kt + 1) * 128;
            vreg[0] = *(const bf16x8*)(vs);
            vreg[1] = *(const bf16x8*)(vs + 8);
            vreg[2] = *(const bf16x8*)(vs + 2048);
            vreg[3] = *(const bf16x8*)(vs + 2048 + 8);
        }

        floatx4 S[8];
        #pragma unroll
        for (int jt = 0; jt < 8; ++jt) {
            int co = (g ^ ((m >> 1) & 3)) * 8;
            bf16x8 kf0 = *(const bf16x8*)&Ks[0][jt * 16 + m][co];
            bf16x8 kf1 = *(const bf16x8*)&Ks[1][jt * 16 + m][co];
            floatx4 z = {0.f, 0.f, 0.f, 0.f};
            z = MFMA32(kf0, qb0, z);
            S[jt] = MFMA32(kf1, qb1, z);
        }

        const bool last = (kt == ktmax);
        if (last) {
            int qr = (qs & 1) * 64 + w * 16 + m;
            #pragma unroll
            for (int jt = 0; jt < 8; ++jt)
                #pragma unroll
                for (int r = 0; r < 4; ++r)
                    if (jt * 16 + g * 4 + r > qr) S[jt][r] = -1e30f;
        }
        bf16x4 pv[8];
        #pragma unroll
        for (int jt = 0; jt < 8; ++jt) {
            bf16x4 t;
            #pragma unroll
            for (int r = 0; r < 4; ++r) {
                float p2 = __expf(S[jt][r]);   // q pre-scaled; exp(-1e30)=0
                l_s += p2;
                t[r] = (__bf16)p2;
            }
            pv[jt] = t;
        }

        #pragma unroll
        for (int jt = 0; jt < 8; ++jt)
            #pragma unroll
            for (int jd = 0; jd < 4; ++jd) {
                bf16x4 vf = *(const bf16x4*)&Vt3[jt][jd * 16 + m]
                        [((g >> 1) ^ ((m >> 2) & 1)) * 8 + ((g & 1) ^ ((m >> 3) & 1)) * 4];
                O[jd] = mfma16(vf, pv[jt], O[jd]);
            }
    }

    float lsum = l_s;
    lsum += __shfl_xor(lsum, 16, 64);
    lsum += __shfl_xor(lsum, 32, 64);
    float inv = 1.0f / lsum;
    int qrow = qs * 64 + w * 16 + m;
    #pragma unroll
    for (int jd = 0; jd < 4; ++jd) {
        bf16x4 o;
        #pragma unroll
        for (int r = 0; r < 4; ++r) o[r] = (__bf16)(O[jd][r] * inv);
        *(bf16x4*)(att + ((size_t)b * TT + qrow) * CC + h * HD + jd * 16 + g * 4) = o;
    }
}

// ---------------------------------------------------------------------------
extern "C" void kernel_launch(void* const* d_in, const int* in_sizes, int n_in,
                              void* d_out, int out_size, void* d_ws, size_t ws_size,
                              hipStream_t stream) {
    const float* x   = (const float*)d_in[0];
    const float* Wq  = (const float*)d_in[1];
    const float* Wk  = (const float*)d_in[2];
    const float* Wv  = (const float*)d_in[3];
    const float* Wo  = (const float*)d_in[4];
    const float* bo  = (const float*)d_in[5];
    const float* W1  = (const float*)d_in[6];
    const float* b1  = (const float*)d_in[7];
    const float* W2  = (const float*)d_in[8];
    const float* b2  = (const float*)d_in[9];
    const float* g1  = (const float*)d_in[10];
    const float* be1 = (const float*)d_in[11];
    const float* g2  = (const float*)d_in[12];
    const float* be2 = (const float*)d_in[13];
    float* out = (float*)d_out;

    char* p = (char*)d_ws;
    char*   pool  = p;          p += (size_t)32 * 1024 * 1024;
    __bf16* qkvb  = (__bf16*)pool;
    __bf16* vtb   = (__bf16*)(pool + (size_t)BT * 3072 * 2);
    __bf16* wop   = (__bf16*)pool;     // 4 x [BT][CC] bf16 partials
    __bf16* ffp   = (__bf16*)pool;     // 4 x [BT][CC] bf16 partials
    __bf16* attb  = (__bf16*)p; p += (size_t)BT * CC * 2;
    __bf16* hb    = (__bf16*)p; p += (size_t)BT * CC * 2;
    float*  x2    = (float*)p;  p += (size_t)BT * CC * 4;
    __bf16* ffb   = (__bf16*)p; p += (size_t)BT * 4096 * 2;
    __bf16* WqkvT = (__bf16*)p; p += (size_t)3072 * 1024 * 2;
    __bf16* WoT   = (__bf16*)p; p += (size_t)1024 * 1024 * 2;
    __bf16* W1T   = (__bf16*)p; p += (size_t)4096 * 1024 * 2;
    __bf16* W2T   = (__bf16*)p; p += (size_t)1024 * 4096 * 2;

    // fused weight transposes + ln1
    transpose_ln<<<16384, 256, 0, stream>>>(Wq, Wk, Wv, Wo, W1, W2,
                                            WqkvT, WoT, W1T, W2T,
                                            x, g1, be1, hb);
    // fused QKV projection; V written transposed into vtb; q pre-scaled
    gemm256<1, __bf16, false, false, true><<<dim3(12, 16), 512, 0, stream>>>(
        hb, WqkvT, nullptr, qkvb, vtb, BT, 3072, 1024);
    attn_mfma6<<<1024, 256, 0, stream>>>(qkvb, vtb, attb);
    // out proj: split-K=4 bf16 partials (full 256-block grid)
    gemm256<4, __bf16, false, false, false><<<dim3(4, 16, 4), 512, 0, stream>>>(
        attb, WoT, nullptr, wop, nullptr, BT, 1024, 1024);
    reduce_wo_ln<<<BT, 256, 0, stream>>>(wop, bo, x, g2, be2, x2, hb);
    // ffn1 + bias + relu
    gemm256<1, __bf16, true, true, false><<<dim3(16, 16), 512, 0, stream>>>(
        hb, W1T, b1, ffb, nullptr, BT, 4096, 1024);
    // ffn2: split-K=4 bf16 partials
    gemm256<4, __bf16, false, false, false><<<dim3(4, 16, 4), 512, 0, stream>>>(
        ffb, W2T, nullptr, ffp, nullptr, BT, 1024, 4096);
    reduce_ffn<<<BT, 256, 0, stream>>>(ffp, b2, x2, out);
}

// Round 6
// 319.602 us; speedup vs baseline: 1.0306x; 1.0306x over previous
//
#include <hip/hip_runtime.h>
#include <hip/hip_bf16.h>
#include <math.h>

#define BB 2
#define TT 2048
#define CC 1024
#define NH 16
#define HD 64
#define BT (BB*TT)          // 4096 rows
#define LN_EPS 1e-5f
#define ATT_SCALE 0.03125f  // C^-0.5 (reference scales by full C, not head_size)

typedef __bf16 bf16x8 __attribute__((ext_vector_type(8)));
typedef __bf16 bf16x4 __attribute__((ext_vector_type(4)));
typedef short shortx4 __attribute__((ext_vector_type(4)));
typedef float floatx4 __attribute__((ext_vector_type(4)));

__device__ __forceinline__ void gl_lds16(const __bf16* g, __bf16* l) {
    __builtin_amdgcn_global_load_lds((const __attribute__((address_space(1))) void*)g,
                                     (__attribute__((address_space(3))) void*)l,
                                     16, 0, 0);
}

#define MFMA32(a, b, c) __builtin_amdgcn_mfma_f32_16x16x32_bf16(a, b, c, 0, 0, 0)

#if __has_builtin(__builtin_amdgcn_mfma_f32_16x16x16_bf16)
__device__ __forceinline__ floatx4 mfma16(bf16x4 a, bf16x4 b, floatx4 c) {
    return __builtin_amdgcn_mfma_f32_16x16x16_bf16(a, b, c, 0, 0, 0);
}
#else
__device__ __forceinline__ floatx4 mfma16(bf16x4 a, bf16x4 b, floatx4 c) {
    return __builtin_amdgcn_mfma_f32_16x16x16bf16_1k(
        __builtin_bit_cast(shortx4, a), __builtin_bit_cast(shortx4, b), c, 0, 0, 0);
}
#endif

#define BARRIER() __builtin_amdgcn_s_barrier()
#define MEMF()  asm volatile("" ::: "memory")
#define VM4()   asm volatile("s_waitcnt vmcnt(4)" ::: "memory")
#define VM0()   asm volatile("s_waitcnt vmcnt(0)" ::: "memory")

// XCD-aware block remap (grid totals are multiples of 8 -> bijective).
__device__ __forceinline__ void swizzle_xcd(int& xb, int& yb, int& zb) {
    int nx = gridDim.x, ny = gridDim.y;
    int total = nx * ny * (int)gridDim.z;
    int lin = blockIdx.x + nx * (blockIdx.y + ny * blockIdx.z);
    int c = lin & 7, s = lin >> 3;
    int idx = c * (total >> 3) + s;
    xb = idx % nx;
    yb = (idx / nx) % ny;
    zb = idx / (nx * ny);
}

// ---------------------------------------------------------------------------
// Fused: all weight transposes (idx < 12288) + ln1 (idx >= 12288).
// ---------------------------------------------------------------------------
__global__ __launch_bounds__(256) void transpose_ln(
        const float* __restrict__ Wq, const float* __restrict__ Wk,
        const float* __restrict__ Wv, const float* __restrict__ Wo,
        const float* __restrict__ W1, const float* __restrict__ W2,
        __bf16* __restrict__ WqkvT, __bf16* __restrict__ WoT,
        __bf16* __restrict__ W1T, __bf16* __restrict__ W2T,
        const float* __restrict__ x, const float* __restrict__ g1,
        const float* __restrict__ be1, __bf16* __restrict__ hb) {
    __shared__ float t[32][33];
    __shared__ float rs_[4], rss_[4];
    __shared__ float mu_s, inv_s;
    int idx = blockIdx.x;
    if (idx >= 12288) {
        int row = idx - 12288;
        const float4* xr = (const float4*)(x + (size_t)row * CC);
        float4 v = xr[threadIdx.x];
        float s  = v.x + v.y + v.z + v.w;
        float ss = v.x*v.x + v.y*v.y + v.z*v.z + v.w*v.w;
        #pragma unroll
        for (int off = 32; off; off >>= 1) {
            s  += __shfl_down(s, off);
            ss += __shfl_down(ss, off);
        }
        int lane = threadIdx.x & 63, wid = threadIdx.x >> 6;
        if (lane == 0) { rs_[wid] = s; rss_[wid] = ss; }
        __syncthreads();
        if (threadIdx.x == 0) {
            float S  = rs_[0] + rs_[1] + rs_[2] + rs_[3];
            float SS = rss_[0] + rss_[1] + rss_[2] + rss_[3];
            float mu  = S * (1.0f / CC);
            float var = SS * (1.0f / CC) - mu * mu;
            mu_s  = mu;
            inv_s = rsqrtf(var + LN_EPS);
        }
        __syncthreads();
        float mu = mu_s, inv = inv_s;
        float4 gv = ((const float4*)g1)[threadIdx.x];
        float4 bv = ((const float4*)be1)[threadIdx.x];
        bf16x4 o;
        o[0] = (__bf16)((v.x - mu) * inv * gv.x + bv.x);
        o[1] = (__bf16)((v.y - mu) * inv * gv.y + bv.y);
        o[2] = (__bf16)((v.z - mu) * inv * gv.z + bv.z);
        o[3] = (__bf16)((v.w - mu) * inv * gv.w + bv.w);
        *(bf16x4*)(hb + (size_t)row * CC + threadIdx.x * 4) = o;
        return;
    }
    const float* src; __bf16* dst; int K, N, tn, tk;
    if (idx < 3072) {
        int wsel = idx >> 10, local = idx & 1023;
        src = (wsel == 0) ? Wq : (wsel == 1 ? Wk : Wv);
        dst = WqkvT + (size_t)wsel * 1024 * 1024;
        K = 1024; N = 1024; tn = local & 31; tk = local >> 5;
    } else if (idx < 4096) {
        int local = idx - 3072;
        src = Wo; dst = WoT; K = 1024; N = 1024; tn = local & 31; tk = local >> 5;
    } else if (idx < 8192) {
        int local = idx - 4096;
        src = W1; dst = W1T; K = 1024; N = 4096; tn = local & 127; tk = local >> 7;
    } else {
        int local = idx - 8192;
        src = W2; dst = W2T; K = 4096; N = 1024; tn = local & 31; tk = local >> 5;
    }
    int n0 = tn * 32, k0 = tk * 32;
    int tx = threadIdx.x & 31, ty = threadIdx.x >> 5;
    #pragma unroll
    for (int r = ty; r < 32; r += 8)
        t[r][tx] = src[(size_t)(k0 + r) * N + n0 + tx];
    __syncthreads();
    #pragma unroll
    for (int r = ty; r < 32; r += 8)
        dst[(size_t)(n0 + r) * K + k0 + tx] = (__bf16)t[tx][r];
}

// ---------------------------------------------------------------------------
// Reduce 4 bf16 split-K partials + bias + residual -> x2 (fp32), then LN -> hb.
// ---------------------------------------------------------------------------
__global__ __launch_bounds__(256) void reduce_wo_ln(const __bf16* __restrict__ P,
                                                    const float* __restrict__ bo,
                                                    const float* __restrict__ x,
                                                    const float* __restrict__ g2,
                                                    const float* __restrict__ be2,
                                                    float* __restrict__ x2,
                                                    __bf16* __restrict__ hb) {
    int row = blockIdx.x;
    int c = threadIdx.x * 4;
    const size_t S = (size_t)BT * CC;
    float4 xb = *(const float4*)(x + (size_t)row * CC + c);
    float4 bb = *(const float4*)(bo + c);
    float4 v;
    v.x = xb.x + bb.x;
    v.y = xb.y + bb.y;
    v.z = xb.z + bb.z;
    v.w = xb.w + bb.w;
    #pragma unroll
    for (int z = 0; z < 4; ++z) {
        bf16x4 a = *(const bf16x4*)(P + z * S + (size_t)row * CC + c);
        v.x += (float)a[0]; v.y += (float)a[1]; v.z += (float)a[2]; v.w += (float)a[3];
    }
    *(float4*)(x2 + (size_t)row * CC + c) = v;

    float s  = v.x + v.y + v.z + v.w;
    float ss = v.x*v.x + v.y*v.y + v.z*v.z + v.w*v.w;
    #pragma unroll
    for (int off = 32; off; off >>= 1) {
        s  += __shfl_down(s, off);
        ss += __shfl_down(ss, off);
    }
    __shared__ float rs_[4], rss_[4];
    __shared__ float mu_s, inv_s;
    int lane = threadIdx.x & 63, wid = threadIdx.x >> 6;
    if (lane == 0) { rs_[wid] = s; rss_[wid] = ss; }
    __syncthreads();
    if (threadIdx.x == 0) {
        float S_  = rs_[0] + rs_[1] + rs_[2] + rs_[3];
        float SS = rss_[0] + rss_[1] + rss_[2] + rss_[3];
        float mu  = S_ * (1.0f / CC);
        float var = SS * (1.0f / CC) - mu * mu;
        mu_s  = mu;
        inv_s = rsqrtf(var + LN_EPS);
    }
    __syncthreads();
    float mu = mu_s, inv = inv_s;
    float4 gv = ((const float4*)g2)[threadIdx.x];
    float4 bv = ((const float4*)be2)[threadIdx.x];
    bf16x4 o;
    o[0] = (__bf16)((v.x - mu) * inv * gv.x + bv.x);
    o[1] = (__bf16)((v.y - mu) * inv * gv.y + bv.y);
    o[2] = (__bf16)((v.z - mu) * inv * gv.z + bv.z);
    o[3] = (__bf16)((v.w - mu) * inv * gv.w + bv.w);
    *(bf16x4*)(hb + (size_t)row * CC + c) = o;
}

// ---------------------------------------------------------------------------
// Reduce 4 bf16 split-K partials + bias + residual(x2) -> out (fp32).
// ---------------------------------------------------------------------------
__global__ __launch_bounds__(256) void reduce_ffn(const __bf16* __restrict__ P,
                                                  const float* __restrict__ b2,
                                                  const float* __restrict__ x2,
                                                  float* __restrict__ out) {
    int row = blockIdx.x;
    int c = threadIdx.x * 4;
    const size_t S = (size_t)BT * CC;
    float4 v = *(const float4*)(x2 + (size_t)row * CC + c);
    float4 bb = *(const float4*)(b2 + c);
    v.x += bb.x; v.y += bb.y; v.z += bb.z; v.w += bb.w;
    #pragma unroll
    for (int z = 0; z < 4; ++z) {
        bf16x4 a = *(const bf16x4*)(P + z * S + (size_t)row * CC + c);
        v.x += (float)a[0]; v.y += (float)a[1]; v.z += (float)a[2]; v.w += (float)a[3];
    }
    *(float4*)(out + (size_t)row * CC + c) = v;
}

// ---------------------------------------------------------------------------
// 256x256-tile / BK=64 / 8-wave / 8-phase counted-vmcnt GEMM.
// Round-14 change: REMOVED the explicit lgkmcnt(0) full drain before each
// MFMA cluster. Round-5 PMC showed phase time = LDS service (~700cy) + MFMA
// (516cy) in SUM (MfmaUtil 30.6% == 516/1556): the drain serialized the
// pipes. The compiler's automatic per-use lgkmcnt(N) lets the first MFMA
// start when its own operands land, overlapping remaining ds_reads with
// compute. WAR/RAW audit: every phase's stage target is disjoint from its
// own read region; cross-phase RAW covered by the counted VM4 FIFO ledger
// (unchanged); phase-N reads all retire by end of phase-N MFMA (every loaded
// reg is consumed there), so phase-N+1 stages can't overwrite pending reads.
// Operand reuse across phases: Q00(A0+B0), Q01(B1), Q11(A1), Q10(none).
// VSPLIT epilogue pre-scales q columns (col<1024) by 2^-5 (= C^-0.5).
// ---------------------------------------------------------------------------
__device__ __forceinline__ void stage_half(const __bf16* __restrict__ mat, int row0,
                                           int ldk, int k0, __bf16* lds, int tid) {
    int r = tid >> 3;                       // 0..63
    int lch = (tid & 7) ^ (r & 7);          // logical k-chunk for phys chunk tid&7
    const __bf16* gp = mat + (size_t)(row0 + r) * ldk + k0 + lch * 8;
    gl_lds16(gp, lds + tid * 8);                           // rows 0..63
    gl_lds16(gp + (size_t)64 * ldk, lds + 4096 + tid * 8); // rows 64..127
}

__device__ __forceinline__ void load_a(const __bf16* As_, int qr, int wr, int m, int g,
                                       bf16x8 (&fa)[4][2]) {
    #pragma unroll
    for (int i = 0; i < 4; ++i) {
        int ra = qr * 128 + wr * 64 + i * 16 + m;
        #pragma unroll
        for (int kk = 0; kk < 2; ++kk)
            fa[i][kk] = *(const bf16x8*)&As_[ra * 64 + (((kk * 4 + g) ^ (m & 7)) * 8)];
    }
}

__device__ __forceinline__ void load_b(const __bf16* Bs_, int qc, int wc, int m, int g,
                                       bf16x8 (&fb)[2][2]) {
    #pragma unroll
    for (int j = 0; j < 2; ++j) {
        int rb = qc * 128 + wc * 32 + j * 16 + m;
        #pragma unroll
        for (int kk = 0; kk < 2; ++kk)
            fb[j][kk] = *(const bf16x8*)&Bs_[rb * 64 + (((kk * 4 + g) ^ (m & 7)) * 8)];
    }
}

__device__ __forceinline__ void mfma_q(bf16x8 (&fa)[4][2], bf16x8 (&fb)[2][2],
                                       floatx4 (&a)[4][2]) {
    __builtin_amdgcn_s_setprio(1);
    #pragma unroll
    for (int i = 0; i < 4; ++i)
        #pragma unroll
        for (int j = 0; j < 2; ++j)
            #pragma unroll
            for (int kk = 0; kk < 2; ++kk)
                a[i][j] = MFMA32(fa[i][kk], fb[j][kk], a[i][j]);
    __builtin_amdgcn_s_setprio(0);
}

template<int SK, typename OT, bool BIAS, bool RELU, bool VSPLIT>
__global__ __launch_bounds__(512, 2) void gemm256(const __bf16* __restrict__ A,
                                                  const __bf16* __restrict__ Bt,
                                                  const float* __restrict__ bias,
                                                  OT* __restrict__ C,
                                                  __bf16* __restrict__ vt,
                                                  int M, int N, int K) {
    __shared__ __bf16 As[2][16384];   // [buf][256 rows x 64], 32 KiB each
    __shared__ __bf16 Bs[2][16384];
    int bx, by, bz;
    swizzle_xcd(bx, by, bz);
    const int tid = threadIdx.x;
    const int l = tid & 63, w = tid >> 6;
    const int m = l & 15, g = l >> 4;
    const int wr = w >> 2, wc = w & 3;          // 2x4 wave grid
    const int m0 = by * 256, n0 = bx * 256;
    const int Keff = K / SK;
    const int kb = (SK > 1) ? bz * Keff : 0;
    const int iters = Keff >> 7;                // 2 K-tiles (128) per iter

    floatx4 acc[2][2][4][2];
    #pragma unroll
    for (int a = 0; a < 2; ++a)
        #pragma unroll
        for (int b = 0; b < 2; ++b)
            #pragma unroll
            for (int i = 0; i < 4; ++i)
                #pragma unroll
                for (int j = 0; j < 2; ++j) {
                    floatx4 z = {0.f, 0.f, 0.f, 0.f};
                    acc[a][b][i][j] = z;
                }

    // prologue: t0 fully + t1.{A-lo, B-hi}; vmcnt(4) retires t0's 8 loads.
    stage_half(A,  m0,       K, kb,      &As[0][0],    tid);  // t0.A-lo
    stage_half(Bt, n0,       K, kb,      &Bs[0][0],    tid);  // t0.B-lo
    stage_half(Bt, n0 + 128, K, kb,      &Bs[0][8192], tid);  // t0.B-hi
    stage_half(A,  m0 + 128, K, kb,      &As[0][8192], tid);  // t0.A-hi
    stage_half(A,  m0,       K, kb + 64, &As[1][0],    tid);  // t1.A-lo
    stage_half(Bt, n0 + 128, K, kb + 64, &Bs[1][8192], tid);  // t1.B-hi
    VM4(); BARRIER(); MEMF();

    bf16x8 fa[4][2], fbA[2][2], fbB[2][2];

    for (int it = 0; it < iters; ++it) {
        const bool lastI = (it == iters - 1);
        const int kB = kb + (2 * it + 1) * 64;  // tile tb = 2it+1 (buf1)
        const int kC = kB + 64;                 // tile tc = 2it+2 (buf0)
        const int kD = kC + 64;                 // tile td = 2it+3 (buf1)

        // ---- buf0 (tile ta) ----
        load_a(&As[0][0], 0, wr, m, g, fa);
        load_b(&Bs[0][0], 0, wc, m, g, fbA);
        stage_half(Bt, n0, K, kB, &Bs[1][0], tid);               // tb.B-lo
        MEMF(); BARRIER(); mfma_q(fa, fbA, acc[0][0]); BARRIER(); MEMF();
        load_b(&Bs[0][0], 1, wc, m, g, fbB);
        stage_half(A, m0 + 128, K, kB, &As[1][8192], tid);       // tb.A-hi
        MEMF(); BARRIER(); mfma_q(fa, fbB, acc[0][1]); BARRIER(); MEMF();
        load_a(&As[0][0], 1, wr, m, g, fa);
        if (!lastI) stage_half(A, m0, K, kC, &As[0][0], tid);    // tc.A-lo
        MEMF(); BARRIER(); mfma_q(fa, fbB, acc[1][1]); BARRIER(); MEMF();
        if (!lastI) { stage_half(Bt, n0 + 128, K, kC, &Bs[0][8192], tid); // tc.B-hi
                      VM4(); }
        else VM0();                              // drain: tb fully resident
        BARRIER(); mfma_q(fa, fbA, acc[1][0]); BARRIER(); MEMF();

        // ---- buf1 (tile tb) ----
        load_a(&As[1][0], 0, wr, m, g, fa);
        load_b(&Bs[1][0], 0, wc, m, g, fbA);
        if (!lastI) stage_half(Bt, n0, K, kC, &Bs[0][0], tid);   // tc.B-lo
        MEMF(); BARRIER(); mfma_q(fa, fbA, acc[0][0]); BARRIER(); MEMF();
        load_b(&Bs[1][0], 1, wc, m, g, fbB);
        if (!lastI) stage_half(A, m0 + 128, K, kC, &As[0][8192], tid); // tc.A-hi
        MEMF(); BARRIER(); mfma_q(fa, fbB, acc[0][1]); BARRIER(); MEMF();
        load_a(&As[1][0], 1, wr, m, g, fa);
        if (!lastI) stage_half(A, m0, K, kD, &As[1][0], tid);    // td.A-lo
        MEMF(); BARRIER(); mfma_q(fa, fbB, acc[1][1]); BARRIER(); MEMF();
        if (!lastI) { stage_half(Bt, n0 + 128, K, kD, &Bs[1][8192], tid); // td.B-hi
                      VM4(); }                   // retires tc; td in flight
        BARRIER(); mfma_q(fa, fbA, acc[1][0]); BARRIER(); MEMF();
    }

    // ---- epilogue ----
    if (SK > 1) {
        __bf16* P = (__bf16*)C + (size_t)bz * M * N;
        #pragma unroll
        for (int qr = 0; qr < 2; ++qr)
            #pragma unroll
            for (int i = 0; i < 4; ++i) {
                int row = m0 + qr * 128 + wr * 64 + i * 16 + g * 4;
                #pragma unroll
                for (int qc = 0; qc < 2; ++qc)
                    #pragma unroll
                    for (int j = 0; j < 2; ++j) {
                        int col = n0 + qc * 128 + wc * 32 + j * 16 + m;
                        #pragma unroll
                        for (int r = 0; r < 4; ++r)
                            P[(size_t)(row + r) * N + col] = (__bf16)acc[qr][qc][i][j][r];
                    }
            }
    } else if (VSPLIT && n0 >= 2048) {
        #pragma unroll
        for (int qr = 0; qr < 2; ++qr)
            #pragma unroll
            for (int i = 0; i < 4; ++i) {
                int row = m0 + qr * 128 + wr * 64 + i * 16 + g * 4;
                int bb = row >> 11, t0 = row & 2047;
                #pragma unroll
                for (int qc = 0; qc < 2; ++qc)
                    #pragma unroll
                    for (int j = 0; j < 2; ++j) {
                        int cv = n0 + qc * 128 + wc * 32 + j * 16 + m - 2048;
                        bf16x4 o;
                        #pragma unroll
                        for (int r = 0; r < 4; ++r) o[r] = (__bf16)acc[qr][qc][i][j][r];
                        *(bf16x4*)(vt + ((size_t)(bb * NH + (cv >> 6)) * HD + (cv & 63)) * 2048 + t0) = o;
                    }
            }
    } else {
        #pragma unroll
        for (int qr = 0; qr < 2; ++qr)
            #pragma unroll
            for (int i = 0; i < 4; ++i) {
                int row = m0 + qr * 128 + wr * 64 + i * 16 + g * 4;
                #pragma unroll
                for (int qc = 0; qc < 2; ++qc)
                    #pragma unroll
                    for (int j = 0; j < 2; ++j) {
                        int col = n0 + qc * 128 + wc * 32 + j * 16 + m;
                        float bv = BIAS ? bias[col] : 0.0f;
                        #pragma unroll
                        for (int r = 0; r < 4; ++r) {
                            float vo = acc[qr][qc][i][j][r] + bv;
                            if (RELU) vo = fmaxf(vo, 0.0f);
                            if (VSPLIT && col < 1024) vo *= ATT_SCALE;  // pre-scale q
                            C[(size_t)(row + r) * N + col] = (OT)vo;
                        }
                    }
            }
    }
}

// ---------------------------------------------------------------------------
// Flash attention v5 (round-4 kernel, best measured at 41.5us — reverted
// verbatim after round-5's V-reg-staging regression). 64-row q-subtiles,
// 4 blocks/CU, 2-barrier gl_lds staging, proven layouts.
// q is pre-scaled by C^-0.5 in the QKV epilogue -> softmax skips the mul.
// ---------------------------------------------------------------------------
__global__ __launch_bounds__(256, 4) void attn_mfma5(const __bf16* __restrict__ qkv,
                                                     const __bf16* __restrict__ vt,
                                                     __bf16* __restrict__ att) {
    const int lin = blockIdx.x;
    const int q0 = lin & 15, h = (lin >> 4) & 15, b = (lin >> 8) & 1, half = lin >> 9;
    const int qs = half ? 31 - q0 : q0;     // 64-row q-subtile, 0..31

    const int tid = threadIdx.x;
    const int l = tid & 63, w = tid >> 6;   // wave w owns q-rows qs*64 + w*16 ..+15
    const int m = l & 15, g = l >> 4;

    __shared__ __bf16 Ks[2][128][32];   // [d-half][k-row][32], 4-chunk XOR swz
    __shared__ __bf16 Vt3[8][64][16];   // [k16][d][k-elem]

    const __bf16* qp = qkv + (size_t)b * TT * 3072 + h * HD;
    const __bf16* kp = qp + 1024;
    const __bf16* vh = vt + (size_t)(b * NH + h) * HD * 2048;

    bf16x8 qb0, qb1;
    {
        int qrow = qs * 64 + w * 16 + m;
        qb0 = *(const bf16x8*)(qp + (size_t)qrow * 3072 + g * 8);
        qb1 = *(const bf16x8*)(qp + (size_t)qrow * 3072 + 32 + g * 8);
    }

    floatx4 O[4];
    float l_s = 0.0f;
    #pragma unroll
    for (int jd = 0; jd < 4; ++jd) { floatx4 z = {0.f, 0.f, 0.f, 0.f}; O[jd] = z; }

    const int ktmax = qs >> 1;
    for (int kt = 0; kt <= ktmax; ++kt) {
        __syncthreads();
        #pragma unroll
        for (int c = 0; c < 4; ++c) {
            int idx = w * 4 + c;
            int dh = idx >> 3, k16 = idx & 7;
            gl_lds16(kp + (size_t)(kt * 128 + k16 * 16 + (l >> 2)) * 3072
                        + dh * 32 + (((l & 3) ^ ((l >> 3) & 3)) * 8),
                     (__bf16*)Ks + dh * 4096 + k16 * 512);
        }
        #pragma unroll
        for (int c = 0; c < 4; ++c) {
            int idx = w * 4 + c;
            int jt = idx >> 1, dhf = idx & 1;
            gl_lds16(vh + (size_t)(dhf * 32 + (l >> 1)) * 2048 + kt * 128
                        + jt * 16 + (((l & 1) ^ ((l >> 3) & 1)) * 8),
                     (__bf16*)Vt3 + jt * 1024 + dhf * 512);
        }
        __syncthreads();

        floatx4 S[8];
        #pragma unroll
        for (int jt = 0; jt < 8; ++jt) {
            int co = (g ^ ((m >> 1) & 3)) * 8;
            bf16x8 kf0 = *(const bf16x8*)&Ks[0][jt * 16 + m][co];
            bf16x8 kf1 = *(const bf16x8*)&Ks[1][jt * 16 + m][co];
            floatx4 z = {0.f, 0.f, 0.f, 0.f};
            z = MFMA32(kf0, qb0, z);
            S[jt] = MFMA32(kf1, qb1, z);
        }

        const bool last = (kt == ktmax);
        if (last) {
            int qr = (qs & 1) * 64 + w * 16 + m;
            #pragma unroll
            for (int jt = 0; jt < 8; ++jt)
                #pragma unroll
                for (int r = 0; r < 4; ++r)
                    if (jt * 16 + g * 4 + r > qr) S[jt][r] = -1e30f;
        }
        bf16x4 pv[8];
        #pragma unroll
        for (int jt = 0; jt < 8; ++jt) {
            bf16x4 t;
            #pragma unroll
            for (int r = 0; r < 4; ++r) {
                float p = __expf(S[jt][r]);   // q pre-scaled; exp(-1e30)=0
                l_s += p;
                t[r] = (__bf16)p;
            }
            pv[jt] = t;
        }

        #pragma unroll
        for (int jt = 0; jt < 8; ++jt)
            #pragma unroll
            for (int jd = 0; jd < 4; ++jd) {
                bf16x4 vf = *(const bf16x4*)&Vt3[jt][jd * 16 + m]
                                [((g >> 1) ^ ((m >> 2) & 1)) * 8 + (g & 1) * 4];
                O[jd] = mfma16(vf, pv[jt], O[jd]);
            }
    }

    float lsum = l_s;
    lsum += __shfl_xor(lsum, 16, 64);
    lsum += __shfl_xor(lsum, 32, 64);
    float inv = 1.0f / lsum;
    int qrow = qs * 64 + w * 16 + m;
    #pragma unroll
    for (int jd = 0; jd < 4; ++jd) {
        bf16x4 o;
        #pragma unroll
        for (int r = 0; r < 4; ++r) o[r] = (__bf16)(O[jd][r] * inv);
        *(bf16x4*)(att + ((size_t)b * TT + qrow) * CC + h * HD + jd * 16 + g * 4) = o;
    }
}

// ---------------------------------------------------------------------------
extern "C" void kernel_launch(void* const* d_in, const int* in_sizes, int n_in,
                              void* d_out, int out_size, void* d_ws, size_t ws_size,
                              hipStream_t stream) {
    const float* x   = (const float*)d_in[0];
    const float* Wq  = (const float*)d_in[1];
    const float* Wk  = (const float*)d_in[2];
    const float* Wv  = (const float*)d_in[3];
    const float* Wo  = (const float*)d_in[4];
    const float* bo  = (const float*)d_in[5];
    const float* W1  = (const float*)d_in[6];
    const float* b1  = (const float*)d_in[7];
    const float* W2  = (const float*)d_in[8];
    const float* b2  = (const float*)d_in[9];
    const float* g1  = (const float*)d_in[10];
    const float* be1 = (const float*)d_in[11];
    const float* g2  = (const float*)d_in[12];
    const float* be2 = (const float*)d_in[13];
    float* out = (float*)d_out;

    char* p = (char*)d_ws;
    char*   pool  = p;          p += (size_t)32 * 1024 * 1024;
    __bf16* qkvb  = (__bf16*)pool;
    __bf16* vtb   = (__bf16*)(pool + (size_t)BT * 3072 * 2);
    __bf16* wop   = (__bf16*)pool;     // 4 x [BT][CC] bf16 partials
    __bf16* ffp   = (__bf16*)pool;     // 4 x [BT][CC] bf16 partials
    __bf16* attb  = (__bf16*)p; p += (size_t)BT * CC * 2;
    __bf16* hb    = (__bf16*)p; p += (size_t)BT * CC * 2;
    float*  x2    = (float*)p;  p += (size_t)BT * CC * 4;
    __bf16* ffb   = (__bf16*)p; p += (size_t)BT * 4096 * 2;
    __bf16* WqkvT = (__bf16*)p; p += (size_t)3072 * 1024 * 2;
    __bf16* WoT   = (__bf16*)p; p += (size_t)1024 * 1024 * 2;
    __bf16* W1T   = (__bf16*)p; p += (size_t)4096 * 1024 * 2;
    __bf16* W2T   = (__bf16*)p; p += (size_t)1024 * 4096 * 2;

    // fused weight transposes + ln1
    transpose_ln<<<16384, 256, 0, stream>>>(Wq, Wk, Wv, Wo, W1, W2,
                                            WqkvT, WoT, W1T, W2T,
                                            x, g1, be1, hb);
    // fused QKV projection; V written transposed into vtb; q pre-scaled
    gemm256<1, __bf16, false, false, true><<<dim3(12, 16), 512, 0, stream>>>(
        hb, WqkvT, nullptr, qkvb, vtb, BT, 3072, 1024);
    attn_mfma5<<<1024, 256, 0, stream>>>(qkvb, vtb, attb);
    // out proj: split-K=4 bf16 partials (full 256-block grid)
    gemm256<4, __bf16, false, false, false><<<dim3(4, 16, 4), 512, 0, stream>>>(
        attb, WoT, nullptr, wop, nullptr, BT, 1024, 1024);
    reduce_wo_ln<<<BT, 256, 0, stream>>>(wop, bo, x, g2, be2, x2, hb);
    // ffn1 + bias + relu
    gemm256<1, __bf16, true, true, false><<<dim3(16, 16), 512, 0, stream>>>(
        hb, W1T, b1, ffb, nullptr, BT, 4096, 1024);
    // ffn2: split-K=4 bf16 partials
    gemm256<4, __bf16, false, false, false><<<dim3(4, 16, 4), 512, 0, stream>>>(
        ffb, W2T, nullptr, ffp, nullptr, BT, 1024, 4096);
    reduce_ffn<<<BT, 256, 0, stream>>>(ffp, b2, x2, out);
}